// Round 3
// baseline (120.951 us; speedup 1.0000x reference)
//
#include <hip/hip_runtime.h>

// ExpertParallel dispatch+combine collapses to an exact identity permutation:
//   out[n, k, :] = x[n, :]  for k in {0, 1}
// Pure broadcast copy: read 128 MB once, write 256 MB.
// R3: nontemporal hints via clang ext_vector_type (HIP_vector_type rejected by
//     the builtin) + 2x float4 per thread-iteration for deeper MLP.

constexpr int N_TOKENS = 8192;
constexpr int HIDDEN   = 4096;
constexpr int H4       = HIDDEN / 4;           // 1024 vec4 per row
constexpr int TOTAL4   = N_TOKENS * H4;        // 8,388,608 vec4
constexpr int TOTAL_P  = TOTAL4 / 2;           // 4,194,304 pairs (row length even)

typedef float f32x4 __attribute__((ext_vector_type(4)));

__global__ __launch_bounds__(256)
void ExpertParallel_63711544868877_kernel(const f32x4* __restrict__ x4,
                                          f32x4* __restrict__ out4) {
    int idx    = blockIdx.x * blockDim.x + threadIdx.x;
    int stride = gridDim.x * blockDim.x;
    for (int p = idx; p < TOTAL_P; p += stride) {
        int i = p << 1;               // pair -> vec4 index (stays within one row)
        int n = i >> 10;              // i / H4
        int c = i & (H4 - 1);         // i % H4 (even)
        f32x4 v0 = __builtin_nontemporal_load(x4 + i);
        f32x4 v1 = __builtin_nontemporal_load(x4 + i + 1);
        f32x4* o = out4 + (size_t)n * (2 * H4) + c;
        __builtin_nontemporal_store(v0, o);
        __builtin_nontemporal_store(v1, o + 1);
        __builtin_nontemporal_store(v0, o + H4);
        __builtin_nontemporal_store(v1, o + H4 + 1);
    }
}

extern "C" void kernel_launch(void* const* d_in, const int* in_sizes, int n_in,
                              void* d_out, int out_size, void* d_ws, size_t ws_size,
                              hipStream_t stream) {
    const f32x4* x4  = (const f32x4*)d_in[0];   // x: [8192, 4096] f32
    // d_in[1] = expert_indices (unused: permutation cancels)
    // d_in[2] = ep_world_size  (unused)
    f32x4* out4 = (f32x4*)d_out;                // [8192, 2, 4096] f32

    const int block = 256;
    const int grid  = 2048;                     // grid-stride, 8 blocks/CU
    ExpertParallel_63711544868877_kernel<<<grid, block, 0, stream>>>(x4, out4);
}

// Round 4
// 65.072 us; speedup vs baseline: 1.8587x; 1.8587x over previous
//
#include <hip/hip_runtime.h>

// ExpertParallel dispatch+combine collapses to an exact identity permutation:
//   out[n, k, :] = x[n, :]  for k in {0, 1}
// Pure broadcast copy: read 128 MB once, write 256 MB.
// R4: back to strict unit-stride per instruction (R3's pair-stride broke
//     coalescing: lanes at 32B stride = 2x transactions). NT on STORES only
//     (pure streaming write, skip L2 write-allocate). Unroll x2 at +stride
//     offsets (coalescing-preserving MLP). All divisions exact: 8,388,608
//     float4 = 16 x (2048 blocks x 256 threads).

constexpr int N_TOKENS = 8192;
constexpr int HIDDEN   = 4096;
constexpr int H4       = HIDDEN / 4;           // 1024 vec4 per row
constexpr int TOTAL4   = N_TOKENS * H4;        // 8,388,608 vec4

typedef float f32x4 __attribute__((ext_vector_type(4)));

__global__ __launch_bounds__(256)
void ExpertParallel_63711544868877_kernel(const f32x4* __restrict__ x4,
                                          f32x4* __restrict__ out4) {
    const int idx    = blockIdx.x * blockDim.x + threadIdx.x;
    const int stride = gridDim.x * blockDim.x;   // 524,288
    // TOTAL4 / stride == 16 exactly; unroll by 2 -> 8 iterations, no tail.
    for (int i = idx; i < TOTAL4; i += 2 * stride) {
        const int j = i + stride;
        f32x4 v0 = x4[i];                        // cached loads (unit-stride)
        f32x4 v1 = x4[j];
        const int n0 = i >> 10, c0 = i & (H4 - 1);
        const int n1 = j >> 10, c1 = j & (H4 - 1);
        f32x4* o0 = out4 + ((size_t)n0 << 11) + c0;   // n*2*H4 + c
        f32x4* o1 = out4 + ((size_t)n1 << 11) + c1;
        __builtin_nontemporal_store(v0, o0);          // k = 0
        __builtin_nontemporal_store(v0, o0 + H4);     // k = 1
        __builtin_nontemporal_store(v1, o1);
        __builtin_nontemporal_store(v1, o1 + H4);
    }
}

extern "C" void kernel_launch(void* const* d_in, const int* in_sizes, int n_in,
                              void* d_out, int out_size, void* d_ws, size_t ws_size,
                              hipStream_t stream) {
    const f32x4* x4  = (const f32x4*)d_in[0];   // x: [8192, 4096] f32
    // d_in[1] = expert_indices (unused: permutation cancels)
    // d_in[2] = ep_world_size  (unused)
    f32x4* out4 = (f32x4*)d_out;                // [8192, 2, 4096] f32

    const int block = 256;
    const int grid  = 2048;                     // stride = 524,288 vec4
    ExpertParallel_63711544868877_kernel<<<grid, block, 0, stream>>>(x4, out4);
}